// Round 6
// baseline (1115.658 us; speedup 1.0000x reference)
//
#include <hip/hip_runtime.h>
#include <math.h>

typedef __attribute__((ext_vector_type(8))) short short8v;  // 8 bf16
typedef __attribute__((ext_vector_type(4))) float f32x4;
typedef unsigned long long u64;
typedef unsigned short ushort_t;

constexpr int Bb = 4;
constexpr int Ll = 512;
constexpr int Dk = 2048;
constexpr int Vv = 32000;
constexpr int Tt = 1024;
constexpr int Mrows = Bb * Ll;  // 2048

// main GEMM geometry: 256x256 tile, BK=64, 8 waves (2 row x 4 col), 2-phase
constexpr int BM = 256;
constexpr int BN = 256;
constexpr int BK = 64;
constexpr int NKT = Dk / BK;     // 32 K-tiles
constexpr int NBX = Mrows / BM;  // 8
constexpr int NBY = Vv / BN;     // 125
constexpr int NWG = NBX * NBY;   // 1000 (divisible by 8)
constexpr int CHUNK = NWG / 8;   // 125

constexpr int KCAND = 8;          // rescored candidates per row
constexpr int CAND_STRIDE = 500;  // u64 per row; main path uses first 250

// fallback geometry (small-ws path, 128x128 reg-staged)
constexpr int FBM = 128;
constexpr int FBN = 128;
constexpr int FNVB = Vv / FBN;  // 250

// ---- workspace layout (bytes) ----
// winv : f32[32000]        @ 0          (131072 B slot)
// best : u64[2048]         @ 131072     (16384 B)
// sel  : i32[2048*8]       @ 147456     (65536 B)
// cand : u64[2048*500]     @ 262144     (8192000 B)
// Abf  : bf16[2048*2048]   @ 8454144    (8388608 B)
// Wbf  : bf16[32000*2048]  @ 16842752   (131072000 B)  -> total 147914752 B
constexpr size_t WS_NEEDED = 147914752ull;

__device__ __forceinline__ unsigned int fkey(float f) {
    unsigned int u = __float_as_uint(f);
    return (u & 0x80000000u) ? ~u : (u | 0x80000000u);
}
__device__ __forceinline__ void top2(u64& b1, u64& b2, u64 p) {
    if (p > b1) { b2 = b1; b1 = p; }
    else if (p > b2) { b2 = p; }
}
__device__ __forceinline__ u64 shfl64(u64 x, int m) {
    unsigned lo = __shfl_xor((unsigned)x, m, 64);
    unsigned hi = __shfl_xor((unsigned)(x >> 32), m, 64);
    return ((u64)hi << 32) | lo;
}
__device__ __forceinline__ ushort_t bftrunc(float x) {
    return (ushort_t)(__float_as_uint(x) >> 16);
}
// async global->LDS, 16B per lane; lds dst wave-uniform base (HW adds lane*16)
__device__ __forceinline__ void gload_lds16(const void* g, void* l) {
    __builtin_amdgcn_global_load_lds(
        (const __attribute__((address_space(1))) unsigned int*)g,
        (__attribute__((address_space(3))) unsigned int*)l, 16, 0, 0);
}

// ---------------- convert A: f32 -> bf16 row-major ----------------
__global__ __launch_bounds__(256) void convertA_kernel(const float* __restrict__ A,
                                                       ushort_t* __restrict__ Ab) {
    int i = blockIdx.x * blockDim.x + threadIdx.x;  // 8 elems per thread
    const float4* src = (const float4*)A;
    float4 x = src[i * 2], y = src[i * 2 + 1];
    ushort_t o[8] = {bftrunc(x.x), bftrunc(x.y), bftrunc(x.z), bftrunc(x.w),
                     bftrunc(y.x), bftrunc(y.y), bftrunc(y.z), bftrunc(y.w)};
    *(int4*)(Ab + (size_t)i * 8) = *(const int4*)o;
}

// ------------- convert W: f32 -> bf16 row-major, fused winv -------------
__global__ __launch_bounds__(256) void convertW_kernel(const float* __restrict__ W,
                                                       ushort_t* __restrict__ Wb,
                                                       float* __restrict__ winv) {
    int wave = (blockIdx.x * blockDim.x + threadIdx.x) >> 6;
    int lane = threadIdx.x & 63;
    if (wave >= Vv) return;
    const float4* row = (const float4*)(W + (size_t)wave * Dk);
    ushort4* orow = (ushort4*)(Wb + (size_t)wave * Dk);
    float s = 0.f;
#pragma unroll
    for (int i = 0; i < Dk / 4 / 64; ++i) {
        float4 v = row[lane + 64 * i];
        s = fmaf(v.x, v.x, s); s = fmaf(v.y, v.y, s);
        s = fmaf(v.z, v.z, s); s = fmaf(v.w, v.w, s);
        ushort4 o;
        o.x = bftrunc(v.x); o.y = bftrunc(v.y);
        o.z = bftrunc(v.z); o.w = bftrunc(v.w);
        orow[lane + 64 * i] = o;
    }
#pragma unroll
    for (int off = 32; off; off >>= 1) s += __shfl_down(s, off, 64);
    if (lane == 0) winv[wave] = 1.0f / sqrtf(s);
}

// ---------------- wnorm only (fallback path) ----------------
__global__ __launch_bounds__(256) void wnorm_kernel(const float* __restrict__ W,
                                                    float* __restrict__ winv) {
    int wave = (blockIdx.x * blockDim.x + threadIdx.x) >> 6;
    int lane = threadIdx.x & 63;
    if (wave >= Vv) return;
    const float4* row = (const float4*)(W + (size_t)wave * Dk);
    float s = 0.f;
#pragma unroll
    for (int i = 0; i < Dk / 4 / 64; ++i) {
        float4 v = row[lane + 64 * i];
        s = fmaf(v.x, v.x, s); s = fmaf(v.y, v.y, s);
        s = fmaf(v.z, v.z, s); s = fmaf(v.w, v.w, s);
    }
#pragma unroll
    for (int off = 32; off; off >>= 1) s += __shfl_down(s, off, 64);
    if (lane == 0) winv[wave] = 1.0f / sqrtf(s);
}

__global__ void init_best_kernel(u64* __restrict__ best) {
    int i = blockIdx.x * blockDim.x + threadIdx.x;
    if (i < Mrows) best[i] = 0ull;
}

// ========== Kernel 3 (main): 256x256 2-phase bf16 GEMM + per-block top-2 ==========
// Ab[2048][2048] bf16, Wb[32000][2048] bf16 -> cand[row][125][2] packed u64.
// LDS fragment-linear layout: block fb = sub*2+kk (sub 0..15, kk 0..1) at ushort
// offset fb*512; lane l owns 8 bf16 at l*8 -> (row = sub*16+(l&15),
// k = kk*32+(l>>4)*8..+7). gload_lds writes it directly (lane*16B linear).
// Loop: stage(t+1) FIRST, compute(t), one __syncthreads per tile (drains
// vmcnt+lgkmcnt) -> staging latency hides under 512 MFMA/block-tile.
__global__ __launch_bounds__(512, 2) void score_topk_kernel(
    const ushort_t* __restrict__ Ab, const ushort_t* __restrict__ Wb,
    const float* __restrict__ winv, u64* __restrict__ cand) {
    __shared__ __align__(16) ushort_t Alds[2][16384];  // 64 KB
    __shared__ __align__(16) ushort_t Wlds[2][16384];  // 64 KB

    // XCD-aware bijective swizzle: 1000 = 8 x 125; one W-panel's 8 row-blocks
    // stay on one XCD's L2.
    const int orig = blockIdx.x;
    const int swz = (orig & 7) * CHUNK + (orig >> 3);
    const int bx = swz & (NBX - 1);
    const int by = swz >> 3;
    const int row0 = bx * BM;
    const int v0 = by * BN;

    const int tid = threadIdx.x;
    const int lane = tid & 63;
    const int w = tid >> 6;   // 0..7
    const int wr = w >> 2;    // 0..1  -> rows wr*128..+127
    const int wc = w & 3;     // 0..3  -> cols wc*64..+63

    const int rsub = lane & 15;
    const int ksub = (lane >> 4) * 8;

    // this wave stages fragment-blocks fb = w*4+q of both A and W
    const ushort_t* srcA[4];
    const ushort_t* srcW[4];
#pragma unroll
    for (int q = 0; q < 4; ++q) {
        const int fb = w * 4 + q, sub = fb >> 1, kk = fb & 1;
        srcA[q] = Ab + (size_t)(row0 + sub * 16 + rsub) * Dk + kk * 32 + ksub;
        srcW[q] = Wb + (size_t)(v0 + sub * 16 + rsub) * Dk + kk * 32 + ksub;
    }

    auto stage = [&](int buf, int t) {
        const int k0 = t * BK;
#pragma unroll
        for (int q = 0; q < 4; ++q) {
            const int fb = w * 4 + q;
            gload_lds16(srcA[q] + k0, &Alds[buf][fb * 512]);
            gload_lds16(srcW[q] + k0, &Wlds[buf][fb * 512]);
        }
    };

    f32x4 acc[8][4];
#pragma unroll
    for (int i = 0; i < 8; ++i)
#pragma unroll
        for (int j = 0; j < 4; ++j) acc[i][j] = (f32x4){0.f, 0.f, 0.f, 0.f};

    stage(0, 0);
    __syncthreads();  // tile 0 resident
    int cur = 0;
    for (int t = 0; t < NKT; ++t) {
        if (t + 1 < NKT) stage(cur ^ 1, t + 1);  // issue next tile's loads FIRST
        const short8v* Ap = (const short8v*)&Alds[cur][0];
        const short8v* Wp = (const short8v*)&Wlds[cur][0];
#pragma unroll
        for (int kk = 0; kk < 2; ++kk) {
            short8v a[8], b[4];
#pragma unroll
            for (int mf = 0; mf < 8; ++mf)
                a[mf] = Ap[((wr * 8 + mf) * 2 + kk) * 64 + lane];
#pragma unroll
            for (int nf = 0; nf < 4; ++nf)
                b[nf] = Wp[((wc * 4 + nf) * 2 + kk) * 64 + lane];
            __builtin_amdgcn_s_setprio(1);
#pragma unroll
            for (int mf = 0; mf < 8; ++mf)
#pragma unroll
                for (int nf = 0; nf < 4; ++nf)
                    acc[mf][nf] = __builtin_amdgcn_mfma_f32_16x16x32_bf16(
                        a[mf], b[nf], acc[mf][nf], 0, 0, 0);
            __builtin_amdgcn_s_setprio(0);
        }
        __syncthreads();  // my reads done; everyone's stage(t+1) drained (vmcnt 0)
        cur ^= 1;
    }

    // ---- epilogue: scale by winv, per-row top-2 within this 256-col block ----
    const int cb = lane & 15;
    float wv[4];
#pragma unroll
    for (int nf = 0; nf < 4; ++nf) wv[nf] = winv[v0 + wc * 64 + nf * 16 + cb];

    u64(*red)[8] = (u64(*)[8]) & Alds[0][0];  // 256 rows x 8 u64 = 16 KB alias
#pragma unroll
    for (int mf = 0; mf < 8; ++mf) {
#pragma unroll
        for (int reg = 0; reg < 4; ++reg) {
            u64 b1 = 0, b2 = 0;
#pragma unroll
            for (int nf = 0; nf < 4; ++nf) {
                float s = acc[mf][nf][reg] * wv[nf];
                int v = v0 + wc * 64 + nf * 16 + cb;
                u64 p = ((u64)fkey(s) << 32) | (unsigned)(Vv - 1 - v);
                top2(b1, b2, p);
            }
#pragma unroll
            for (int m = 1; m < 16; m <<= 1) {
                u64 o1 = shfl64(b1, m);
                u64 o2 = shfl64(b2, m);
                top2(b1, b2, o1);
                top2(b1, b2, o2);
            }
            if (cb == 0) {
                int rl = wr * 128 + mf * 16 + ((lane >> 4) << 2) + reg;
                red[rl][wc * 2] = b1;
                red[rl][wc * 2 + 1] = b2;
            }
        }
    }
    __syncthreads();
    if (tid < BM) {
        u64 b1 = red[tid][0], b2 = red[tid][1];
#pragma unroll
        for (int j = 2; j < 8; ++j) top2(b1, b2, red[tid][j]);
        u64* c = cand + (size_t)(row0 + tid) * CAND_STRIDE + by * 2;
        c[0] = b1;
        c[1] = b2;
    }
}

// ------ fallback epilogue (128x128 path) ------
template <typename LdsT>
__device__ __forceinline__ void topk_epilogue_f(f32x4 (&acc)[4][4], LdsT* ldsbase,
                                                const float* __restrict__ winv,
                                                u64* __restrict__ cand, int row0, int v0,
                                                int vby, int tid, int lane, int wr,
                                                int wc) {
    const int cbase = v0 + wc * 64 + (lane & 15);
    float wv[4];
#pragma unroll
    for (int nf = 0; nf < 4; ++nf) wv[nf] = winv[cbase + nf * 16];

    u64(*red)[4] = (u64(*)[4])ldsbase;
#pragma unroll
    for (int mf = 0; mf < 4; ++mf) {
#pragma unroll
        for (int reg = 0; reg < 4; ++reg) {
            u64 b1 = 0, b2 = 0;
#pragma unroll
            for (int nf = 0; nf < 4; ++nf) {
                float s = acc[mf][nf][reg] * wv[nf];
                int v = cbase + nf * 16;
                u64 p = ((u64)fkey(s) << 32) | (unsigned)(Vv - 1 - v);
                top2(b1, b2, p);
            }
#pragma unroll
            for (int m = 1; m < 16; m <<= 1) {
                u64 o1 = shfl64(b1, m);
                u64 o2 = shfl64(b2, m);
                top2(b1, b2, o1);
                top2(b1, b2, o2);
            }
            if ((lane & 15) == 0) {
                int rl = wr * 64 + mf * 16 + ((lane >> 4) << 2) + reg;
                red[rl][wc * 2] = b1;
                red[rl][wc * 2 + 1] = b2;
            }
        }
    }
    __syncthreads();
    if (tid < FBM) {
        u64 b1 = red[tid][0], b2 = red[tid][1];
        top2(b1, b2, red[tid][2]);
        top2(b1, b2, red[tid][3]);
        u64* c = cand + (size_t)(row0 + tid) * CAND_STRIDE + vby * 2;
        c[0] = b1;
        c[1] = b2;
    }
}

// ---------- Kernel 3 (fallback, small ws): reg-staged f32->bf16 GEMM ----------
__global__ __launch_bounds__(256) void score_topk_fallback(
    const float* __restrict__ A, const float* __restrict__ W,
    const float* __restrict__ winv, u64* __restrict__ cand) {
    __shared__ __align__(16) short Albuf[4096];
    __shared__ __align__(16) short Wlbuf[4096];

    const int tid = threadIdx.x;
    const int row0 = blockIdx.x * FBM;
    const int v0 = blockIdx.y * FBN;
    const int lane = tid & 63;
    const int wid = tid >> 6;
    const int wr = wid >> 1, wc = wid & 1;

    const int rA = ((tid >> 6) << 4) + (tid & 15);
    const int kk = ((tid >> 4) & 3) * 8;

    const float* pa = A + (size_t)(row0 + rA) * Dk + kk;
    const float* pw = W + (size_t)(v0 + rA) * Dk + kk;

    float4 fa0, fa1, fa2, fa3, fw0, fw1, fw2, fw3;
    auto ld4 = [](const float* p) { return *(const float4*)p; };
    auto load_regs = [&](int k0) {
        fa0 = ld4(pa + k0); fa1 = ld4(pa + k0 + 4);
        fa2 = ld4(pa + k0 + (size_t)64 * Dk); fa3 = ld4(pa + k0 + (size_t)64 * Dk + 4);
        fw0 = ld4(pw + k0); fw1 = ld4(pw + k0 + 4);
        fw2 = ld4(pw + k0 + (size_t)64 * Dk); fw3 = ld4(pw + k0 + (size_t)64 * Dk + 4);
    };
    auto pk = [](float lo, float hi) {
        return (int)((__float_as_uint(lo) >> 16) | (__float_as_uint(hi) & 0xFFFF0000u));
    };
    auto cv = [&](float4 a, float4 b) {
        int4 r; r.x = pk(a.x, a.y); r.y = pk(a.z, a.w);
        r.z = pk(b.x, b.y); r.w = pk(b.z, b.w); return r;
    };
    auto write_lds = [&]() {
        *(int4*)(Albuf + tid * 8) = cv(fa0, fa1);
        *(int4*)(Albuf + tid * 8 + 2048) = cv(fa2, fa3);
        *(int4*)(Wlbuf + tid * 8) = cv(fw0, fw1);
        *(int4*)(Wlbuf + tid * 8 + 2048) = cv(fw2, fw3);
    };

    f32x4 acc[4][4];
#pragma unroll
    for (int i = 0; i < 4; ++i)
#pragma unroll
        for (int j = 0; j < 4; ++j) acc[i][j] = (f32x4){0.f, 0.f, 0.f, 0.f};

    load_regs(0);
    for (int kt = 0; kt < Dk / 32; ++kt) {
        write_lds();
        __syncthreads();
        if (kt + 1 < Dk / 32) load_regs((kt + 1) * 32);
        short8v af[4], bf[4];
        const short8v* Ap = (const short8v*)Albuf;
        const short8v* Wp = (const short8v*)Wlbuf;
#pragma unroll
        for (int mf = 0; mf < 4; ++mf) af[mf] = Ap[(wr * 4 + mf) * 64 + lane];
#pragma unroll
        for (int nf = 0; nf < 4; ++nf) bf[nf] = Wp[(wc * 4 + nf) * 64 + lane];
#pragma unroll
        for (int mf = 0; mf < 4; ++mf)
#pragma unroll
            for (int nf = 0; nf < 4; ++nf)
                acc[mf][nf] = __builtin_amdgcn_mfma_f32_16x16x32_bf16(
                    af[mf], bf[nf], acc[mf][nf], 0, 0, 0);
        __syncthreads();
    }

    topk_epilogue_f(acc, Albuf, winv, cand, row0, v0, blockIdx.y, tid, lane, wr, wc);
}

// ---------------- Kernel 4: per-row top-8 of nents candidates ----------------
__global__ __launch_bounds__(256) void topk_kernel(const u64* __restrict__ cand,
                                                   int* __restrict__ sel, int nents) {
    int row = blockIdx.x * 4 + (threadIdx.x >> 6);
    int lane = threadIdx.x & 63;
    if (row >= Mrows) return;
    const u64* c = cand + (size_t)row * CAND_STRIDE;
    u64 v[8];
#pragma unroll
    for (int i = 0; i < 8; ++i) {
        int idx = lane + i * 64;
        v[i] = (idx < nents) ? c[idx] : 0ull;
    }
#pragma unroll
    for (int it = 0; it < KCAND; ++it) {
        u64 lm = 0;
#pragma unroll
        for (int i = 0; i < 8; ++i) lm = v[i] > lm ? v[i] : lm;
#pragma unroll
        for (int m = 32; m; m >>= 1) {
            u64 o = shfl64(lm, m);
            lm = o > lm ? o : lm;
        }
#pragma unroll
        for (int i = 0; i < 8; ++i)
            if (v[i] == lm) v[i] = 0;  // packed values unique -> removes one
        if (lane == 0) sel[row * KCAND + it] = Vv - 1 - (int)(unsigned)(lm & 0xFFFFFFFFu);
    }
}

// ---------------- Kernel 5: exact f32 rescore of top-8 ----------------
__global__ __launch_bounds__(256) void rescore_kernel(
    const float* __restrict__ A, const float* __restrict__ W,
    const float* __restrict__ winv, const int* __restrict__ sel,
    u64* __restrict__ best) {
    int gw = (int)((blockIdx.x * blockDim.x + threadIdx.x) >> 6);
    int lane = threadIdx.x & 63;
    if (gw >= Mrows * KCAND) return;
    int row = gw >> 3, c = gw & 7;
    int v = sel[row * KCAND + c];
    const float4* a = (const float4*)(A + (size_t)row * Dk);
    const float4* w = (const float4*)(W + (size_t)v * Dk);
    float s = 0.f;
#pragma unroll
    for (int i = 0; i < Dk / 4 / 64; ++i) {
        float4 x = a[lane + 64 * i], y = w[lane + 64 * i];
        s = fmaf(x.x, y.x, s); s = fmaf(x.y, y.y, s);
        s = fmaf(x.z, y.z, s); s = fmaf(x.w, y.w, s);
    }
#pragma unroll
    for (int m = 32; m; m >>= 1) s += __shfl_xor(s, m, 64);
    if (lane == 0) {
        u64 p = ((u64)fkey(s * winv[v]) << 32) | (unsigned)(Vv - 1 - v);
        atomicMax(best + row, p);
    }
}

// ---------------- Kernel 6: blend + emit quantize_index ----------------
__global__ __launch_bounds__(256) void blend_kernel(
    const float* __restrict__ emb, const int* __restrict__ ids,
    const u64* __restrict__ best, float* __restrict__ out) {
    int row = blockIdx.x;
    int b = row / Tt;
    int t = row % Tt;
    int idx;
    if (t < Ll) {
        idx = Vv - 1 - (int)(best[b * Ll + t] & 0xFFFFFFFFu);
    } else {
        idx = ids[row];
    }
    const float4* src = (const float4*)(emb + (size_t)idx * Dk);
    float4* dst = (float4*)(out + (size_t)row * Dk);
    for (int i = threadIdx.x; i < Dk / 4; i += blockDim.x) dst[i] = src[i];
    if (t < Ll && threadIdx.x == 0) {
        out[(size_t)Bb * Tt * Dk + (size_t)(b * Ll + t)] = (float)idx;
    }
}

extern "C" void kernel_launch(void* const* d_in, const int* in_sizes, int n_in,
                              void* d_out, int out_size, void* d_ws, size_t ws_size,
                              hipStream_t stream) {
    const float* encoder_outs = (const float*)d_in[0];
    const float* embed_weight = (const float*)d_in[1];
    const int* input_ids = (const int*)d_in[2];

    float* out = (float*)d_out;

    float* winv = (float*)d_ws;
    u64* best = (u64*)((char*)d_ws + 131072);
    int* sel = (int*)((char*)d_ws + 147456);
    u64* cand = (u64*)((char*)d_ws + 262144);
    ushort_t* Abf = (ushort_t*)((char*)d_ws + 8454144);
    ushort_t* Wbf = (ushort_t*)((char*)d_ws + 16842752);

    init_best_kernel<<<(Mrows + 255) / 256, 256, 0, stream>>>(best);

    if (ws_size >= WS_NEEDED) {
        convertA_kernel<<<Mrows * Dk / 8 / 256, 256, 0, stream>>>(encoder_outs, Abf);
        convertW_kernel<<<Vv * 64 / 256, 256, 0, stream>>>(embed_weight, Wbf, winv);
        score_topk_kernel<<<NWG, 512, 0, stream>>>(Abf, Wbf, winv, cand);
        topk_kernel<<<Mrows / 4, 256, 0, stream>>>(cand, sel, 2 * NBY);  // 250
    } else {
        wnorm_kernel<<<Vv * 64 / 256, 256, 0, stream>>>(embed_weight, winv);
        dim3 grid(Mrows / FBM, Vv / FBN);
        score_topk_fallback<<<grid, 256, 0, stream>>>(encoder_outs, embed_weight, winv,
                                                      cand);
        topk_kernel<<<Mrows / 4, 256, 0, stream>>>(cand, sel, 2 * FNVB);  // 500
    }
    rescore_kernel<<<Mrows * KCAND / 4, 256, 0, stream>>>(encoder_outs, embed_weight,
                                                          winv, sel, best);
    blend_kernel<<<Bb * Tt, 256, 0, stream>>>(embed_weight, input_ids, best, out);
}

// Round 7
// 1055.446 us; speedup vs baseline: 1.0570x; 1.0570x over previous
//
#include <hip/hip_runtime.h>
#include <math.h>

typedef __attribute__((ext_vector_type(8))) short short8v;  // 8 bf16
typedef __attribute__((ext_vector_type(4))) float f32x4;
typedef unsigned long long u64;
typedef unsigned short ushort_t;

constexpr int Bb = 4;
constexpr int Ll = 512;
constexpr int Dk = 2048;
constexpr int Vv = 32000;
constexpr int Tt = 1024;
constexpr int Mrows = Bb * Ll;  // 2048

// main GEMM geometry: 256x256 tile, BK=64, 8 waves (2 row x 4 col), 4-phase/K-tile
constexpr int BM = 256;
constexpr int BN = 256;
constexpr int BK = 64;
constexpr int NKT = Dk / BK;     // 32 K-tiles
constexpr int NBX = Mrows / BM;  // 8
constexpr int NBY = Vv / BN;     // 125
constexpr int NWG = NBX * NBY;   // 1000 (divisible by 8)
constexpr int CHUNK = NWG / 8;   // 125

constexpr int KCAND = 8;          // rescored candidates per row
constexpr int CAND_STRIDE = 500;  // u64 per row; main path uses first 250

// fallback geometry (small-ws path, 128x128 reg-staged)
constexpr int FBM = 128;
constexpr int FBN = 128;
constexpr int FNVB = Vv / FBN;  // 250

// ---- workspace layout (bytes) ----
// winv : f32[32000]        @ 0          (131072 B slot)
// best : u64[2048]         @ 131072     (16384 B)
// sel  : i32[2048*8]       @ 147456     (65536 B)
// cand : u64[2048*500]     @ 262144     (8192000 B)
// Abf  : bf16[2048*2048]   @ 8454144    (8388608 B)
// Wbf  : bf16[32000*2048]  @ 16842752   (131072000 B)  -> total 147914752 B
constexpr size_t WS_NEEDED = 147914752ull;

__device__ __forceinline__ unsigned int fkey(float f) {
    unsigned int u = __float_as_uint(f);
    return (u & 0x80000000u) ? ~u : (u | 0x80000000u);
}
__device__ __forceinline__ void top2(u64& b1, u64& b2, u64 p) {
    if (p > b1) { b2 = b1; b1 = p; }
    else if (p > b2) { b2 = p; }
}
__device__ __forceinline__ u64 shfl64(u64 x, int m) {
    unsigned lo = __shfl_xor((unsigned)x, m, 64);
    unsigned hi = __shfl_xor((unsigned)(x >> 32), m, 64);
    return ((u64)hi << 32) | lo;
}
__device__ __forceinline__ ushort_t bftrunc(float x) {
    return (ushort_t)(__float_as_uint(x) >> 16);
}
// async global->LDS, 16B per lane; lds dst wave-uniform base (HW adds lane*16)
__device__ __forceinline__ void gload_lds16(const void* g, void* l) {
    __builtin_amdgcn_global_load_lds(
        (const __attribute__((address_space(1))) unsigned int*)g,
        (__attribute__((address_space(3))) unsigned int*)l, 16, 0, 0);
}

// ---------------- convert A: f32 -> bf16 row-major ----------------
__global__ __launch_bounds__(256) void convertA_kernel(const float* __restrict__ A,
                                                       ushort_t* __restrict__ Ab) {
    int i = blockIdx.x * blockDim.x + threadIdx.x;  // 8 elems per thread
    const float4* src = (const float4*)A;
    float4 x = src[i * 2], y = src[i * 2 + 1];
    ushort_t o[8] = {bftrunc(x.x), bftrunc(x.y), bftrunc(x.z), bftrunc(x.w),
                     bftrunc(y.x), bftrunc(y.y), bftrunc(y.z), bftrunc(y.w)};
    *(int4*)(Ab + (size_t)i * 8) = *(const int4*)o;
}

// ------------- convert W: f32 -> bf16 row-major, fused winv -------------
__global__ __launch_bounds__(256) void convertW_kernel(const float* __restrict__ W,
                                                       ushort_t* __restrict__ Wb,
                                                       float* __restrict__ winv) {
    int wave = (blockIdx.x * blockDim.x + threadIdx.x) >> 6;
    int lane = threadIdx.x & 63;
    if (wave >= Vv) return;
    const float4* row = (const float4*)(W + (size_t)wave * Dk);
    ushort4* orow = (ushort4*)(Wb + (size_t)wave * Dk);
    float s = 0.f;
#pragma unroll
    for (int i = 0; i < Dk / 4 / 64; ++i) {
        float4 v = row[lane + 64 * i];
        s = fmaf(v.x, v.x, s); s = fmaf(v.y, v.y, s);
        s = fmaf(v.z, v.z, s); s = fmaf(v.w, v.w, s);
        ushort4 o;
        o.x = bftrunc(v.x); o.y = bftrunc(v.y);
        o.z = bftrunc(v.z); o.w = bftrunc(v.w);
        orow[lane + 64 * i] = o;
    }
#pragma unroll
    for (int off = 32; off; off >>= 1) s += __shfl_down(s, off, 64);
    if (lane == 0) winv[wave] = 1.0f / sqrtf(s);
}

// ---------------- wnorm only (fallback path) ----------------
__global__ __launch_bounds__(256) void wnorm_kernel(const float* __restrict__ W,
                                                    float* __restrict__ winv) {
    int wave = (blockIdx.x * blockDim.x + threadIdx.x) >> 6;
    int lane = threadIdx.x & 63;
    if (wave >= Vv) return;
    const float4* row = (const float4*)(W + (size_t)wave * Dk);
    float s = 0.f;
#pragma unroll
    for (int i = 0; i < Dk / 4 / 64; ++i) {
        float4 v = row[lane + 64 * i];
        s = fmaf(v.x, v.x, s); s = fmaf(v.y, v.y, s);
        s = fmaf(v.z, v.z, s); s = fmaf(v.w, v.w, s);
    }
#pragma unroll
    for (int off = 32; off; off >>= 1) s += __shfl_down(s, off, 64);
    if (lane == 0) winv[wave] = 1.0f / sqrtf(s);
}

__global__ void init_best_kernel(u64* __restrict__ best) {
    int i = blockIdx.x * blockDim.x + threadIdx.x;
    if (i < Mrows) best[i] = 0ull;
}

// ========== Kernel 3 (main): 256x256 4-phase counted-vmcnt bf16 GEMM + top-2 ==========
// LDS fragment-linear: fb = sub*2+kk (sub=row/16 0..15, kk = k32-chunk 0..1) at ushort
// offset fb*512; lane l owns 8 bf16 -> (row = sub*16+(l&15), k = kk*32+(l>>4)*8..+7).
// Per K-tile: 4 phases keyed (kk, nh). Each phase: [vmcnt wait] -> barrier ->
// 10 ds_read_b128 + 2 gload_lds(stage next tile) -> setprio(1) 16 MFMA setprio(0).
// Stage order A-kk0,W-kk0,A-kk1,W-kk1 matches consumption -> vmcnt(4) at phases 1,3
// is exact: queue never drains to 0 in the main loop (T3+T4), loads are 3-4 phases
// old at consumption.
__global__ __launch_bounds__(512, 2) void score_topk_kernel(
    const ushort_t* __restrict__ Ab, const ushort_t* __restrict__ Wb,
    const float* __restrict__ winv, u64* __restrict__ cand) {
    __shared__ __align__(16) ushort_t Alds[2][16384];  // 64 KB
    __shared__ __align__(16) ushort_t Wlds[2][16384];  // 64 KB

    // XCD-aware bijective swizzle: 1000 = 8 x 125
    const int orig = blockIdx.x;
    const int swz = (orig & 7) * CHUNK + (orig >> 3);
    const int bx = swz & (NBX - 1);
    const int by = swz >> 3;
    const int row0 = bx * BM;
    const int v0 = by * BN;

    const int tid = threadIdx.x;
    const int lane = tid & 63;
    const int w = tid >> 6;   // 0..7
    const int wr = w >> 2;    // 0..1  -> rows wr*128..+127
    const int wc = w & 3;     // 0..3  -> cols wc*64..+63

    const int rsub = lane & 15;
    const int ksub = (lane >> 4) * 8;

    // stage sources: wave w stages subs {2w, 2w+1} of both A and W
    const ushort_t* sA0 = Ab + (size_t)(row0 + (2 * w) * 16 + rsub) * Dk + ksub;
    const ushort_t* sA1 = Ab + (size_t)(row0 + (2 * w + 1) * 16 + rsub) * Dk + ksub;
    const ushort_t* sW0 = Wb + (size_t)(v0 + (2 * w) * 16 + rsub) * Dk + ksub;
    const ushort_t* sW1 = Wb + (size_t)(v0 + (2 * w + 1) * 16 + rsub) * Dk + ksub;

    auto stageA = [&](int dd, int t1, int kk) {
        const int k0 = t1 * BK + kk * 32;
        gload_lds16(sA0 + k0, &Alds[dd][((2 * w) * 2 + kk) * 512]);
        gload_lds16(sA1 + k0, &Alds[dd][((2 * w + 1) * 2 + kk) * 512]);
    };
    auto stageW = [&](int dd, int t1, int kk) {
        const int k0 = t1 * BK + kk * 32;
        gload_lds16(sW0 + k0, &Wlds[dd][((2 * w) * 2 + kk) * 512]);
        gload_lds16(sW1 + k0, &Wlds[dd][((2 * w + 1) * 2 + kk) * 512]);
    };

    f32x4 acc[8][4];
#pragma unroll
    for (int i = 0; i < 8; ++i)
#pragma unroll
        for (int j = 0; j < 4; ++j) acc[i][j] = (f32x4){0.f, 0.f, 0.f, 0.f};

    // phase body. wmode: -1 none, 4 -> vmcnt(4), 0 -> vmcnt(0). sop: -1 none,
    // 0 stageA kk0, 1 stageW kk0, 2 stageA kk1, 3 stageW kk1 (for tile t1).
    auto phase = [&](int d, int kk, int nh, int wmode, int sop, int t1) {
        if (wmode == 4) asm volatile("s_waitcnt vmcnt(4)" ::: "memory");
        else if (wmode == 0) asm volatile("s_waitcnt vmcnt(0)" ::: "memory");
        __builtin_amdgcn_s_barrier();
        __builtin_amdgcn_sched_barrier(0);
        asm volatile("" ::: "memory");

        const short8v* Ap = (const short8v*)&Alds[d][0];
        const short8v* Wp = (const short8v*)&Wlds[d][0];
        short8v a[8], b[2];
#pragma unroll
        for (int mf = 0; mf < 8; ++mf)
            a[mf] = Ap[((wr * 8 + mf) * 2 + kk) * 64 + lane];
#pragma unroll
        for (int j = 0; j < 2; ++j)
            b[j] = Wp[((wc * 4 + nh * 2 + j) * 2 + kk) * 64 + lane];

        if (sop == 0) stageA(d ^ 1, t1, 0);
        else if (sop == 1) stageW(d ^ 1, t1, 0);
        else if (sop == 2) stageA(d ^ 1, t1, 1);
        else if (sop == 3) stageW(d ^ 1, t1, 1);

        __builtin_amdgcn_s_setprio(1);
#pragma unroll
        for (int mf = 0; mf < 8; ++mf)
#pragma unroll
            for (int j = 0; j < 2; ++j)
                acc[mf][nh * 2 + j] = __builtin_amdgcn_mfma_f32_16x16x32_bf16(
                    a[mf], b[j], acc[mf][nh * 2 + j], 0, 0, 0);
        __builtin_amdgcn_s_setprio(0);
        __builtin_amdgcn_sched_barrier(0);
        asm volatile("s_waitcnt lgkmcnt(0)" ::: "memory");
    };

    // prologue: stage tile 0 in consumption order (FIFO: Akk0, Wkk0, Akk1, Wkk1)
    stageA(0, 0, 0);
    stageW(0, 0, 0);
    stageA(0, 0, 1);
    stageW(0, 0, 1);

    int d = 0;
    for (int t = 0; t < NKT; ++t) {
        const bool last = (t == NKT - 1);
        const int t1 = t + 1;
        phase(d, 0, 0, 4, last ? -1 : 0, t1);           // (kk0,nh0) wait vmcnt(4)
        phase(d, 0, 1, -1, last ? -1 : 1, t1);          // (kk0,nh1)
        phase(d, 1, 0, last ? 0 : 4, last ? -1 : 2, t1);// (kk1,nh0) wait 4 (or drain)
        phase(d, 1, 1, -1, last ? -1 : 3, t1);          // (kk1,nh1)
        d ^= 1;
    }
    __syncthreads();  // all reads done before epilogue LDS reuse

    // ---- epilogue: scale by winv, per-row top-2 within this 256-col block ----
    const int cb = lane & 15;
    float wv[4];
#pragma unroll
    for (int nf = 0; nf < 4; ++nf) wv[nf] = winv[v0 + wc * 64 + nf * 16 + cb];

    u64(*red)[8] = (u64(*)[8]) & Alds[0][0];  // 256 rows x 8 u64 = 16 KB alias
#pragma unroll
    for (int mf = 0; mf < 8; ++mf) {
#pragma unroll
        for (int reg = 0; reg < 4; ++reg) {
            u64 b1 = 0, b2 = 0;
#pragma unroll
            for (int nf = 0; nf < 4; ++nf) {
                float s = acc[mf][nf][reg] * wv[nf];
                int v = v0 + wc * 64 + nf * 16 + cb;
                u64 p = ((u64)fkey(s) << 32) | (unsigned)(Vv - 1 - v);
                top2(b1, b2, p);
            }
#pragma unroll
            for (int m = 1; m < 16; m <<= 1) {
                u64 o1 = shfl64(b1, m);
                u64 o2 = shfl64(b2, m);
                top2(b1, b2, o1);
                top2(b1, b2, o2);
            }
            if (cb == 0) {
                int rl = wr * 128 + mf * 16 + ((lane >> 4) << 2) + reg;
                red[rl][wc * 2] = b1;
                red[rl][wc * 2 + 1] = b2;
            }
        }
    }
    __syncthreads();
    if (tid < BM) {
        u64 b1 = red[tid][0], b2 = red[tid][1];
#pragma unroll
        for (int j = 2; j < 8; ++j) top2(b1, b2, red[tid][j]);
        u64* c = cand + (size_t)(row0 + tid) * CAND_STRIDE + by * 2;
        c[0] = b1;
        c[1] = b2;
    }
}

// ------ fallback epilogue (128x128 path) ------
template <typename LdsT>
__device__ __forceinline__ void topk_epilogue_f(f32x4 (&acc)[4][4], LdsT* ldsbase,
                                                const float* __restrict__ winv,
                                                u64* __restrict__ cand, int row0, int v0,
                                                int vby, int tid, int lane, int wr,
                                                int wc) {
    const int cbase = v0 + wc * 64 + (lane & 15);
    float wv[4];
#pragma unroll
    for (int nf = 0; nf < 4; ++nf) wv[nf] = winv[cbase + nf * 16];

    u64(*red)[4] = (u64(*)[4])ldsbase;
#pragma unroll
    for (int mf = 0; mf < 4; ++mf) {
#pragma unroll
        for (int reg = 0; reg < 4; ++reg) {
            u64 b1 = 0, b2 = 0;
#pragma unroll
            for (int nf = 0; nf < 4; ++nf) {
                float s = acc[mf][nf][reg] * wv[nf];
                int v = cbase + nf * 16;
                u64 p = ((u64)fkey(s) << 32) | (unsigned)(Vv - 1 - v);
                top2(b1, b2, p);
            }
#pragma unroll
            for (int m = 1; m < 16; m <<= 1) {
                u64 o1 = shfl64(b1, m);
                u64 o2 = shfl64(b2, m);
                top2(b1, b2, o1);
                top2(b1, b2, o2);
            }
            if ((lane & 15) == 0) {
                int rl = wr * 64 + mf * 16 + ((lane >> 4) << 2) + reg;
                red[rl][wc * 2] = b1;
                red[rl][wc * 2 + 1] = b2;
            }
        }
    }
    __syncthreads();
    if (tid < FBM) {
        u64 b1 = red[tid][0], b2 = red[tid][1];
        top2(b1, b2, red[tid][2]);
        top2(b1, b2, red[tid][3]);
        u64* c = cand + (size_t)(row0 + tid) * CAND_STRIDE + vby * 2;
        c[0] = b1;
        c[1] = b2;
    }
}

// ---------- Kernel 3 (fallback, small ws): reg-staged f32->bf16 GEMM ----------
__global__ __launch_bounds__(256) void score_topk_fallback(
    const float* __restrict__ A, const float* __restrict__ W,
    const float* __restrict__ winv, u64* __restrict__ cand) {
    __shared__ __align__(16) short Albuf[4096];
    __shared__ __align__(16) short Wlbuf[4096];

    const int tid = threadIdx.x;
    const int row0 = blockIdx.x * FBM;
    const int v0 = blockIdx.y * FBN;
    const int lane = tid & 63;
    const int wid = tid >> 6;
    const int wr = wid >> 1, wc = wid & 1;

    const int rA = ((tid >> 6) << 4) + (tid & 15);
    const int kk = ((tid >> 4) & 3) * 8;

    const float* pa = A + (size_t)(row0 + rA) * Dk + kk;
    const float* pw = W + (size_t)(v0 + rA) * Dk + kk;

    float4 fa0, fa1, fa2, fa3, fw0, fw1, fw2, fw3;
    auto ld4 = [](const float* p) { return *(const float4*)p; };
    auto load_regs = [&](int k0) {
        fa0 = ld4(pa + k0); fa1 = ld4(pa + k0 + 4);
        fa2 = ld4(pa + k0 + (size_t)64 * Dk); fa3 = ld4(pa + k0 + (size_t)64 * Dk + 4);
        fw0 = ld4(pw + k0); fw1 = ld4(pw + k0 + 4);
        fw2 = ld4(pw + k0 + (size_t)64 * Dk); fw3 = ld4(pw + k0 + (size_t)64 * Dk + 4);
    };
    auto pk = [](float lo, float hi) {
        return (int)((__float_as_uint(lo) >> 16) | (__float_as_uint(hi) & 0xFFFF0000u));
    };
    auto cv = [&](float4 a, float4 b) {
        int4 r; r.x = pk(a.x, a.y); r.y = pk(a.z, a.w);
        r.z = pk(b.x, b.y); r.w = pk(b.z, b.w); return r;
    };
    auto write_lds = [&]() {
        *(int4*)(Albuf + tid * 8) = cv(fa0, fa1);
        *(int4*)(Albuf + tid * 8 + 2048) = cv(fa2, fa3);
        *(int4*)(Wlbuf + tid * 8) = cv(fw0, fw1);
        *(int4*)(Wlbuf + tid * 8 + 2048) = cv(fw2, fw3);
    };

    f32x4 acc[4][4];
#pragma unroll
    for (int i = 0; i < 4; ++i)
#pragma unroll
        for (int j = 0; j < 4; ++j) acc[i][j] = (f32x4){0.f, 0.f, 0.f, 0.f};

    load_regs(0);
    for (int kt = 0; kt < Dk / 32; ++kt) {
        write_lds();
        __syncthreads();
        if (kt + 1 < Dk / 32) load_regs((kt + 1) * 32);
        short8v af[4], bf[4];
        const short8v* Ap = (const short8v*)Albuf;
        const short8v* Wp = (const short8v*)Wlbuf;
#pragma unroll
        for (int mf = 0; mf < 4; ++mf) af[mf] = Ap[(wr * 4 + mf) * 64 + lane];
#pragma unroll
        for (int nf = 0; nf < 4; ++nf) bf[nf] = Wp[(wc * 4 + nf) * 64 + lane];
#pragma unroll
        for (int mf = 0; mf < 4; ++mf)
#pragma unroll
            for (int nf = 0; nf < 4; ++nf)
                acc[mf][nf] = __builtin_amdgcn_mfma_f32_16x16x32_bf16(
                    af[mf], bf[nf], acc[mf][nf], 0, 0, 0);
        __syncthreads();
    }

    topk_epilogue_f(acc, Albuf, winv, cand, row0, v0, blockIdx.y, tid, lane, wr, wc);
}

// ---------------- Kernel 4: per-row top-8 of nents candidates ----------------
__global__ __launch_bounds__(256) void topk_kernel(const u64* __restrict__ cand,
                                                   int* __restrict__ sel, int nents) {
    int row = blockIdx.x * 4 + (threadIdx.x >> 6);
    int lane = threadIdx.x & 63;
    if (row >= Mrows) return;
    const u64* c = cand + (size_t)row * CAND_STRIDE;
    u64 v[8];
#pragma unroll
    for (int i = 0; i < 8; ++i) {
        int idx = lane + i * 64;
        v[i] = (idx < nents) ? c[idx] : 0ull;
    }
#pragma unroll
    for (int it = 0; it < KCAND; ++it) {
        u64 lm = 0;
#pragma unroll
        for (int i = 0; i < 8; ++i) lm = v[i] > lm ? v[i] : lm;
#pragma unroll
        for (int m = 32; m; m >>= 1) {
            u64 o = shfl64(lm, m);
            lm = o > lm ? o : lm;
        }
#pragma unroll
        for (int i = 0; i < 8; ++i)
            if (v[i] == lm) v[i] = 0;  // packed values unique -> removes one
        if (lane == 0) sel[row * KCAND + it] = Vv - 1 - (int)(unsigned)(lm & 0xFFFFFFFFu);
    }
}

// ---------------- Kernel 5: exact f32 rescore of top-8 ----------------
__global__ __launch_bounds__(256) void rescore_kernel(
    const float* __restrict__ A, const float* __restrict__ W,
    const float* __restrict__ winv, const int* __restrict__ sel,
    u64* __restrict__ best) {
    int gw = (int)((blockIdx.x * blockDim.x + threadIdx.x) >> 6);
    int lane = threadIdx.x & 63;
    if (gw >= Mrows * KCAND) return;
    int row = gw >> 3, c = gw & 7;
    int v = sel[row * KCAND + c];
    const float4* a = (const float4*)(A + (size_t)row * Dk);
    const float4* w = (const float4*)(W + (size_t)v * Dk);
    float s = 0.f;
#pragma unroll
    for (int i = 0; i < Dk / 4 / 64; ++i) {
        float4 x = a[lane + 64 * i], y = w[lane + 64 * i];
        s = fmaf(x.x, y.x, s); s = fmaf(x.y, y.y, s);
        s = fmaf(x.z, y.z, s); s = fmaf(x.w, y.w, s);
    }
#pragma unroll
    for (int m = 32; m; m >>= 1) s += __shfl_xor(s, m, 64);
    if (lane == 0) {
        u64 p = ((u64)fkey(s * winv[v]) << 32) | (unsigned)(Vv - 1 - v);
        atomicMax(best + row, p);
    }
}

// ---------------- Kernel 6: blend + emit quantize_index ----------------
__global__ __launch_bounds__(256) void blend_kernel(
    const float* __restrict__ emb, const int* __restrict__ ids,
    const u64* __restrict__ best, float* __restrict__ out) {
    int row = blockIdx.x;
    int b = row / Tt;
    int t = row % Tt;
    int idx;
    if (t < Ll) {
        idx = Vv - 1 - (int)(best[b * Ll + t] & 0xFFFFFFFFu);
    } else {
        idx = ids[row];
    }
    const float4* src = (const float4*)(emb + (size_t)idx * Dk);
    float4* dst = (float4*)(out + (size_t)row * Dk);
    for (int i = threadIdx.x; i < Dk / 4; i += blockDim.x) dst[i] = src[i];
    if (t < Ll && threadIdx.x == 0) {
        out[(size_t)Bb * Tt * Dk + (size_t)(b * Ll + t)] = (float)idx;
    }
}

extern "C" void kernel_launch(void* const* d_in, const int* in_sizes, int n_in,
                              void* d_out, int out_size, void* d_ws, size_t ws_size,
                              hipStream_t stream) {
    const float* encoder_outs = (const float*)d_in[0];
    const float* embed_weight = (const float*)d_in[1];
    const int* input_ids = (const int*)d_in[2];

    float* out = (float*)d_out;

    float* winv = (float*)d_ws;
    u64* best = (u64*)((char*)d_ws + 131072);
    int* sel = (int*)((char*)d_ws + 147456);
    u64* cand = (u64*)((char*)d_ws + 262144);
    ushort_t* Abf = (ushort_t*)((char*)d_ws + 8454144);
    ushort_t* Wbf = (ushort_t*)((char*)d_ws + 16842752);

    init_best_kernel<<<(Mrows + 255) / 256, 256, 0, stream>>>(best);

    if (ws_size >= WS_NEEDED) {
        convertA_kernel<<<Mrows * Dk / 8 / 256, 256, 0, stream>>>(encoder_outs, Abf);
        convertW_kernel<<<Vv * 64 / 256, 256, 0, stream>>>(embed_weight, Wbf, winv);
        score_topk_kernel<<<NWG, 512, 0, stream>>>(Abf, Wbf, winv, cand);
        topk_kernel<<<Mrows / 4, 256, 0, stream>>>(cand, sel, 2 * NBY);  // 250
    } else {
        wnorm_kernel<<<Vv * 64 / 256, 256, 0, stream>>>(embed_weight, winv);
        dim3 grid(Mrows / FBM, Vv / FBN);
        score_topk_fallback<<<grid, 256, 0, stream>>>(encoder_outs, embed_weight, winv,
                                                      cand);
        topk_kernel<<<Mrows / 4, 256, 0, stream>>>(cand, sel, 2 * FNVB);  // 500
    }
    rescore_kernel<<<Mrows * KCAND / 4, 256, 0, stream>>>(encoder_outs, embed_weight,
                                                          winv, sel, best);
    blend_kernel<<<Bb * Tt, 256, 0, stream>>>(embed_weight, input_ids, best, out);
}

// Round 8
// 1034.481 us; speedup vs baseline: 1.0785x; 1.0203x over previous
//
#include <hip/hip_runtime.h>
#include <math.h>

typedef __attribute__((ext_vector_type(8))) short short8v;  // 8 bf16
typedef __attribute__((ext_vector_type(4))) float f32x4;
typedef unsigned long long u64;
typedef unsigned short ushort_t;

constexpr int Bb = 4;
constexpr int Ll = 512;
constexpr int Dk = 2048;
constexpr int Vv = 32000;
constexpr int Tt = 1024;
constexpr int Mrows = Bb * Ll;  // 2048

// main GEMM geometry: 256x256 tile, BK=32, 8 waves (2 row x 4 col),
// 4-deep LDS pipeline, 2 phases/K-tile, counted vmcnt(8) once per tile.
constexpr int BM = 256;
constexpr int BN = 256;
constexpr int BK = 32;
constexpr int NKT = Dk / BK;     // 64 K-tiles
constexpr int NBX = Mrows / BM;  // 8
constexpr int NBY = Vv / BN;     // 125
constexpr int NWG = NBX * NBY;   // 1000 (divisible by 8)
constexpr int CHUNK = NWG / 8;   // 125

constexpr int KCAND = 8;          // rescored candidates per row
constexpr int CAND_STRIDE = 500;  // u64 per row; main path uses first 250

// fallback geometry (small-ws path, 128x128 reg-staged)
constexpr int FBM = 128;
constexpr int FBN = 128;
constexpr int FNVB = Vv / FBN;  // 250

// ---- workspace layout (bytes) ----
// winv : f32[32000]        @ 0          (131072 B slot)
// best : u64[2048]         @ 131072     (16384 B)
// sel  : i32[2048*8]       @ 147456     (65536 B)
// cand : u64[2048*500]     @ 262144     (8192000 B)
// Abf  : bf16[2048*2048]   @ 8454144    (8388608 B)
// Wbf  : bf16[32000*2048]  @ 16842752   (131072000 B)  -> total 147914752 B
constexpr size_t WS_NEEDED = 147914752ull;

__device__ __forceinline__ unsigned int fkey(float f) {
    unsigned int u = __float_as_uint(f);
    return (u & 0x80000000u) ? ~u : (u | 0x80000000u);
}
__device__ __forceinline__ void top2(u64& b1, u64& b2, u64 p) {
    if (p > b1) { b2 = b1; b1 = p; }
    else if (p > b2) { b2 = p; }
}
__device__ __forceinline__ u64 shfl64(u64 x, int m) {
    unsigned lo = __shfl_xor((unsigned)x, m, 64);
    unsigned hi = __shfl_xor((unsigned)(x >> 32), m, 64);
    return ((u64)hi << 32) | lo;
}
__device__ __forceinline__ ushort_t bftrunc(float x) {
    return (ushort_t)(__float_as_uint(x) >> 16);
}
// async global->LDS, 16B per lane; lds dst wave-uniform base (HW adds lane*16)
__device__ __forceinline__ void gload_lds16(const void* g, void* l) {
    __builtin_amdgcn_global_load_lds(
        (const __attribute__((address_space(1))) unsigned int*)g,
        (__attribute__((address_space(3))) unsigned int*)l, 16, 0, 0);
}

// ---------------- convert A: f32 -> bf16 row-major ----------------
__global__ __launch_bounds__(256) void convertA_kernel(const float* __restrict__ A,
                                                       ushort_t* __restrict__ Ab) {
    int i = blockIdx.x * blockDim.x + threadIdx.x;  // 8 elems per thread
    const float4* src = (const float4*)A;
    float4 x = src[i * 2], y = src[i * 2 + 1];
    ushort_t o[8] = {bftrunc(x.x), bftrunc(x.y), bftrunc(x.z), bftrunc(x.w),
                     bftrunc(y.x), bftrunc(y.y), bftrunc(y.z), bftrunc(y.w)};
    *(int4*)(Ab + (size_t)i * 8) = *(const int4*)o;
}

// ------------- convert W: f32 -> bf16 row-major, fused winv -------------
__global__ __launch_bounds__(256) void convertW_kernel(const float* __restrict__ W,
                                                       ushort_t* __restrict__ Wb,
                                                       float* __restrict__ winv) {
    int wave = (blockIdx.x * blockDim.x + threadIdx.x) >> 6;
    int lane = threadIdx.x & 63;
    if (wave >= Vv) return;
    const float4* row = (const float4*)(W + (size_t)wave * Dk);
    ushort4* orow = (ushort4*)(Wb + (size_t)wave * Dk);
    float s = 0.f;
#pragma unroll
    for (int i = 0; i < Dk / 4 / 64; ++i) {
        float4 v = row[lane + 64 * i];
        s = fmaf(v.x, v.x, s); s = fmaf(v.y, v.y, s);
        s = fmaf(v.z, v.z, s); s = fmaf(v.w, v.w, s);
        ushort4 o;
        o.x = bftrunc(v.x); o.y = bftrunc(v.y);
        o.z = bftrunc(v.z); o.w = bftrunc(v.w);
        orow[lane + 64 * i] = o;
    }
#pragma unroll
    for (int off = 32; off; off >>= 1) s += __shfl_down(s, off, 64);
    if (lane == 0) winv[wave] = 1.0f / sqrtf(s);
}

// ---------------- wnorm only (fallback path) ----------------
__global__ __launch_bounds__(256) void wnorm_kernel(const float* __restrict__ W,
                                                    float* __restrict__ winv) {
    int wave = (blockIdx.x * blockDim.x + threadIdx.x) >> 6;
    int lane = threadIdx.x & 63;
    if (wave >= Vv) return;
    const float4* row = (const float4*)(W + (size_t)wave * Dk);
    float s = 0.f;
#pragma unroll
    for (int i = 0; i < Dk / 4 / 64; ++i) {
        float4 v = row[lane + 64 * i];
        s = fmaf(v.x, v.x, s); s = fmaf(v.y, v.y, s);
        s = fmaf(v.z, v.z, s); s = fmaf(v.w, v.w, s);
    }
#pragma unroll
    for (int off = 32; off; off >>= 1) s += __shfl_down(s, off, 64);
    if (lane == 0) winv[wave] = 1.0f / sqrtf(s);
}

__global__ void init_best_kernel(u64* __restrict__ best) {
    int i = blockIdx.x * blockDim.x + threadIdx.x;
    if (i < Mrows) best[i] = 0ull;
}

// ========== Kernel 3 (main): 4-deep pipelined BK=32 bf16 GEMM + top-2 ==========
// LDS per buffer: 16 subtiles (16 rows each) x 512 ushorts; lane l owns 8 bf16 at
// sub*512 + l*8 -> (row = sub*16+(l&15), k = (l>>4)*8..+7). gload_lds-linear.
// Pipeline: stage tile t+3 during tile t (12 loads/wave in flight), wait
// vmcnt(8) once per tile end -> loads are ~3 tiles old at consumption.
// Phase discipline (m201): reads -> [stage] -> barrier -> lgkmcnt(0) ->
// setprio(1) 16 MFMA setprio(0) -> barrier.
__global__ __launch_bounds__(512, 2) void score_topk_kernel(
    const ushort_t* __restrict__ Ab, const ushort_t* __restrict__ Wb,
    const float* __restrict__ winv, u64* __restrict__ cand) {
    __shared__ __align__(16) ushort_t Alds[4][8192];  // 4 bufs x 16 KB
    __shared__ __align__(16) ushort_t Wlds[4][8192];  // 4 bufs x 16 KB

    // XCD-aware bijective swizzle: 1000 = 8 x 125
    const int orig = blockIdx.x;
    const int swz = (orig & 7) * CHUNK + (orig >> 3);
    const int bx = swz & (NBX - 1);
    const int by = swz >> 3;
    const int row0 = bx * BM;
    const int v0 = by * BN;

    const int tid = threadIdx.x;
    const int lane = tid & 63;
    const int w = tid >> 6;   // 0..7
    const int wr = w >> 2;    // 0..1  -> rows wr*128..+127
    const int wc = w & 3;     // 0..3  -> cols wc*64..+63

    const int rsub = lane & 15;
    const int ksub = (lane >> 4) * 8;

    // stage sources: wave w stages subs {2w, 2w+1} of both A and W (4 loads/tile)
    const ushort_t* sA0 = Ab + (size_t)(row0 + (2 * w) * 16 + rsub) * Dk + ksub;
    const ushort_t* sA1 = Ab + (size_t)(row0 + (2 * w + 1) * 16 + rsub) * Dk + ksub;
    const ushort_t* sW0 = Wb + (size_t)(v0 + (2 * w) * 16 + rsub) * Dk + ksub;
    const ushort_t* sW1 = Wb + (size_t)(v0 + (2 * w + 1) * 16 + rsub) * Dk + ksub;

    auto stageA = [&](int buf, int t) {
        const int k0 = t * BK;
        gload_lds16(sA0 + k0, &Alds[buf][(2 * w) * 512]);
        gload_lds16(sA1 + k0, &Alds[buf][(2 * w + 1) * 512]);
    };
    auto stageW = [&](int buf, int t) {
        const int k0 = t * BK;
        gload_lds16(sW0 + k0, &Wlds[buf][(2 * w) * 512]);
        gload_lds16(sW1 + k0, &Wlds[buf][(2 * w + 1) * 512]);
    };

    f32x4 acc[8][4];
#pragma unroll
    for (int i = 0; i < 8; ++i)
#pragma unroll
        for (int j = 0; j < 4; ++j) acc[i][j] = (f32x4){0.f, 0.f, 0.f, 0.f};

    // prologue: 3 tiles in flight (12 loads/wave, FIFO per tile: A,A,W,W)
    stageA(0, 0); stageW(0, 0);
    stageA(1, 1); stageW(1, 1);
    stageA(2, 2); stageW(2, 2);
    asm volatile("s_waitcnt vmcnt(8)" ::: "memory");  // tile 0 landed
    __builtin_amdgcn_s_barrier();

    for (int t = 0; t < NKT; ++t) {
        const int buf = t & 3;
        const bool st = (t + 3 < NKT);
        const short8v* Ap = (const short8v*)&Alds[buf][0];
        const short8v* Wp = (const short8v*)&Wlds[buf][0];
        short8v a[4], b[4], a2[4];

        // ---- phase 0: mf 0..3 ----
#pragma unroll
        for (int i = 0; i < 4; ++i) a[i] = Ap[(wr * 8 + i) * 64 + lane];
#pragma unroll
        for (int j = 0; j < 4; ++j) b[j] = Wp[(wc * 4 + j) * 64 + lane];
        if (st) stageA((t + 3) & 3, t + 3);
        __builtin_amdgcn_s_barrier();
        asm volatile("s_waitcnt lgkmcnt(0)" ::: "memory");
        __builtin_amdgcn_sched_barrier(0);
        __builtin_amdgcn_s_setprio(1);
#pragma unroll
        for (int i = 0; i < 4; ++i)
#pragma unroll
            for (int j = 0; j < 4; ++j)
                acc[i][j] = __builtin_amdgcn_mfma_f32_16x16x32_bf16(a[i], b[j],
                                                                    acc[i][j], 0, 0, 0);
        __builtin_amdgcn_s_setprio(0);
        __builtin_amdgcn_sched_barrier(0);
        __builtin_amdgcn_s_barrier();

        // ---- phase 1: mf 4..7 (reuses b) ----
#pragma unroll
        for (int i = 0; i < 4; ++i) a2[i] = Ap[(wr * 8 + 4 + i) * 64 + lane];
        if (st) stageW((t + 3) & 3, t + 3);
        __builtin_amdgcn_s_barrier();
        asm volatile("s_waitcnt lgkmcnt(0)" ::: "memory");
        __builtin_amdgcn_sched_barrier(0);
        __builtin_amdgcn_s_setprio(1);
#pragma unroll
        for (int i = 0; i < 4; ++i)
#pragma unroll
            for (int j = 0; j < 4; ++j)
                acc[4 + i][j] = __builtin_amdgcn_mfma_f32_16x16x32_bf16(
                    a2[i], b[j], acc[4 + i][j], 0, 0, 0);
        __builtin_amdgcn_s_setprio(0);
        __builtin_amdgcn_sched_barrier(0);
        // counted wait: ensure tile t+1 resident for everyone after the barrier;
        // keep the 2 newest staged tiles in flight (never drain to 0 mid-loop).
        if (t <= NKT - 4) asm volatile("s_waitcnt vmcnt(8)" ::: "memory");
        else if (t == NKT - 3) asm volatile("s_waitcnt vmcnt(4)" ::: "memory");
        else if (t == NKT - 2) asm volatile("s_waitcnt vmcnt(0)" ::: "memory");
        __builtin_amdgcn_s_barrier();
    }
    __syncthreads();  // all LDS reads done before epilogue alias reuse

    // ---- epilogue: scale by winv, per-row top-2 within this 256-col block ----
    const int cb = lane & 15;
    float wv[4];
#pragma unroll
    for (int nf = 0; nf < 4; ++nf) wv[nf] = winv[v0 + wc * 64 + nf * 16 + cb];

    u64(*red)[8] = (u64(*)[8]) & Alds[0][0];  // 256 rows x 8 u64 = 16 KB alias
#pragma unroll
    for (int mf = 0; mf < 8; ++mf) {
#pragma unroll
        for (int reg = 0; reg < 4; ++reg) {
            u64 b1 = 0, b2 = 0;
#pragma unroll
            for (int nf = 0; nf < 4; ++nf) {
                float s = acc[mf][nf][reg] * wv[nf];
                int v = v0 + wc * 64 + nf * 16 + cb;
                u64 p = ((u64)fkey(s) << 32) | (unsigned)(Vv - 1 - v);
                top2(b1, b2, p);
            }
#pragma unroll
            for (int m = 1; m < 16; m <<= 1) {
                u64 o1 = shfl64(b1, m);
                u64 o2 = shfl64(b2, m);
                top2(b1, b2, o1);
                top2(b1, b2, o2);
            }
            if (cb == 0) {
                int rl = wr * 128 + mf * 16 + ((lane >> 4) << 2) + reg;
                red[rl][wc * 2] = b1;
                red[rl][wc * 2 + 1] = b2;
            }
        }
    }
    __syncthreads();
    if (tid < BM) {
        u64 b1 = red[tid][0], b2 = red[tid][1];
#pragma unroll
        for (int j = 2; j < 8; ++j) top2(b1, b2, red[tid][j]);
        u64* c = cand + (size_t)(row0 + tid) * CAND_STRIDE + by * 2;
        c[0] = b1;
        c[1] = b2;
    }
}

// ------ fallback epilogue (128x128 path) ------
template <typename LdsT>
__device__ __forceinline__ void topk_epilogue_f(f32x4 (&acc)[4][4], LdsT* ldsbase,
                                                const float* __restrict__ winv,
                                                u64* __restrict__ cand, int row0, int v0,
                                                int vby, int tid, int lane, int wr,
                                                int wc) {
    const int cbase = v0 + wc * 64 + (lane & 15);
    float wv[4];
#pragma unroll
    for (int nf = 0; nf < 4; ++nf) wv[nf] = winv[cbase + nf * 16];

    u64(*red)[4] = (u64(*)[4])ldsbase;
#pragma unroll
    for (int mf = 0; mf < 4; ++mf) {
#pragma unroll
        for (int reg = 0; reg < 4; ++reg) {
            u64 b1 = 0, b2 = 0;
#pragma unroll
            for (int nf = 0; nf < 4; ++nf) {
                float s = acc[mf][nf][reg] * wv[nf];
                int v = cbase + nf * 16;
                u64 p = ((u64)fkey(s) << 32) | (unsigned)(Vv - 1 - v);
                top2(b1, b2, p);
            }
#pragma unroll
            for (int m = 1; m < 16; m <<= 1) {
                u64 o1 = shfl64(b1, m);
                u64 o2 = shfl64(b2, m);
                top2(b1, b2, o1);
                top2(b1, b2, o2);
            }
            if ((lane & 15) == 0) {
                int rl = wr * 64 + mf * 16 + ((lane >> 4) << 2) + reg;
                red[rl][wc * 2] = b1;
                red[rl][wc * 2 + 1] = b2;
            }
        }
    }
    __syncthreads();
    if (tid < FBM) {
        u64 b1 = red[tid][0], b2 = red[tid][1];
        top2(b1, b2, red[tid][2]);
        top2(b1, b2, red[tid][3]);
        u64* c = cand + (size_t)(row0 + tid) * CAND_STRIDE + vby * 2;
        c[0] = b1;
        c[1] = b2;
    }
}

// ---------- Kernel 3 (fallback, small ws): reg-staged f32->bf16 GEMM ----------
__global__ __launch_bounds__(256) void score_topk_fallback(
    const float* __restrict__ A, const float* __restrict__ W,
    const float* __restrict__ winv, u64* __restrict__ cand) {
    __shared__ __align__(16) short Albuf[4096];
    __shared__ __align__(16) short Wlbuf[4096];

    const int tid = threadIdx.x;
    const int row0 = blockIdx.x * FBM;
    const int v0 = blockIdx.y * FBN;
    const int lane = tid & 63;
    const int wid = tid >> 6;
    const int wr = wid >> 1, wc = wid & 1;

    const int rA = ((tid >> 6) << 4) + (tid & 15);
    const int kk = ((tid >> 4) & 3) * 8;

    const float* pa = A + (size_t)(row0 + rA) * Dk + kk;
    const float* pw = W + (size_t)(v0 + rA) * Dk + kk;

    float4 fa0, fa1, fa2, fa3, fw0, fw1, fw2, fw3;
    auto ld4 = [](const float* p) { return *(const float4*)p; };
    auto load_regs = [&](int k0) {
        fa0 = ld4(pa + k0); fa1 = ld4(pa + k0 + 4);
        fa2 = ld4(pa + k0 + (size_t)64 * Dk); fa3 = ld4(pa + k0 + (size_t)64 * Dk + 4);
        fw0 = ld4(pw + k0); fw1 = ld4(pw + k0 + 4);
        fw2 = ld4(pw + k0 + (size_t)64 * Dk); fw3 = ld4(pw + k0 + (size_t)64 * Dk + 4);
    };
    auto pk = [](float lo, float hi) {
        return (int)((__float_as_uint(lo) >> 16) | (__float_as_uint(hi) & 0xFFFF0000u));
    };
    auto cv = [&](float4 a, float4 b) {
        int4 r; r.x = pk(a.x, a.y); r.y = pk(a.z, a.w);
        r.z = pk(b.x, b.y); r.w = pk(b.z, b.w); return r;
    };
    auto write_lds = [&]() {
        *(int4*)(Albuf + tid * 8) = cv(fa0, fa1);
        *(int4*)(Albuf + tid * 8 + 2048) = cv(fa2, fa3);
        *(int4*)(Wlbuf + tid * 8) = cv(fw0, fw1);
        *(int4*)(Wlbuf + tid * 8 + 2048) = cv(fw2, fw3);
    };

    f32x4 acc[4][4];
#pragma unroll
    for (int i = 0; i < 4; ++i)
#pragma unroll
        for (int j = 0; j < 4; ++j) acc[i][j] = (f32x4){0.f, 0.f, 0.f, 0.f};

    load_regs(0);
    for (int kt = 0; kt < Dk / 32; ++kt) {
        write_lds();
        __syncthreads();
        if (kt + 1 < Dk / 32) load_regs((kt + 1) * 32);
        short8v af[4], bf[4];
        const short8v* Ap = (const short8v*)Albuf;
        const short8v* Wp = (const short8v*)Wlbuf;
#pragma unroll
        for (int mf = 0; mf < 4; ++mf) af[mf] = Ap[(wr * 4 + mf) * 64 + lane];
#pragma unroll
        for (int nf = 0; nf < 4; ++nf) bf[nf] = Wp[(wc * 4 + nf) * 64 + lane];
#pragma unroll
        for (int mf = 0; mf < 4; ++mf)
#pragma unroll
            for (int nf = 0; nf < 4; ++nf)
                acc[mf][nf] = __builtin_amdgcn_mfma_f32_16x16x32_bf16(
                    af[mf], bf[nf], acc[mf][nf], 0, 0, 0);
        __syncthreads();
    }

    topk_epilogue_f(acc, Albuf, winv, cand, row0, v0, blockIdx.y, tid, lane, wr, wc);
}

// ---------------- Kernel 4: per-row top-8 of nents candidates ----------------
__global__ __launch_bounds__(256) void topk_kernel(const u64* __restrict__ cand,
                                                   int* __restrict__ sel, int nents) {
    int row = blockIdx.x * 4 + (threadIdx.x >> 6);
    int lane = threadIdx.x & 63;
    if (row >= Mrows) return;
    const u64* c = cand + (size_t)row * CAND_STRIDE;
    u64 v[8];
#pragma unroll
    for (int i = 0; i < 8; ++i) {
        int idx = lane + i * 64;
        v[i] = (idx < nents) ? c[idx] : 0ull;
    }
#pragma unroll
    for (int it = 0; it < KCAND; ++it) {
        u64 lm = 0;
#pragma unroll
        for (int i = 0; i < 8; ++i) lm = v[i] > lm ? v[i] : lm;
#pragma unroll
        for (int m = 32; m; m >>= 1) {
            u64 o = shfl64(lm, m);
            lm = o > lm ? o : lm;
        }
#pragma unroll
        for (int i = 0; i < 8; ++i)
            if (v[i] == lm) v[i] = 0;  // packed values unique -> removes one
        if (lane == 0) sel[row * KCAND + it] = Vv - 1 - (int)(unsigned)(lm & 0xFFFFFFFFu);
    }
}

// ---------------- Kernel 5: exact f32 rescore of top-8 ----------------
__global__ __launch_bounds__(256) void rescore_kernel(
    const float* __restrict__ A, const float* __restrict__ W,
    const float* __restrict__ winv, const int* __restrict__ sel,
    u64* __restrict__ best) {
    int gw = (int)((blockIdx.x * blockDim.x + threadIdx.x) >> 6);
    int lane = threadIdx.x & 63;
    if (gw >= Mrows * KCAND) return;
    int row = gw >> 3, c = gw & 7;
    int v = sel[row * KCAND + c];
    const float4* a = (const float4*)(A + (size_t)row * Dk);
    const float4* w = (const float4*)(W + (size_t)v * Dk);
    float s = 0.f;
#pragma unroll
    for (int i = 0; i < Dk / 4 / 64; ++i) {
        float4 x = a[lane + 64 * i], y = w[lane + 64 * i];
        s = fmaf(x.x, y.x, s); s = fmaf(x.y, y.y, s);
        s = fmaf(x.z, y.z, s); s = fmaf(x.w, y.w, s);
    }
#pragma unroll
    for (int m = 32; m; m >>= 1) s += __shfl_xor(s, m, 64);
    if (lane == 0) {
        u64 p = ((u64)fkey(s * winv[v]) << 32) | (unsigned)(Vv - 1 - v);
        atomicMax(best + row, p);
    }
}

// ---------------- Kernel 6: blend + emit quantize_index ----------------
__global__ __launch_bounds__(256) void blend_kernel(
    const float* __restrict__ emb, const int* __restrict__ ids,
    const u64* __restrict__ best, float* __restrict__ out) {
    int row = blockIdx.x;
    int b = row / Tt;
    int t = row % Tt;
    int idx;
    if (t < Ll) {
        idx = Vv - 1 - (int)(best[b * Ll + t] & 0xFFFFFFFFu);
    } else {
        idx = ids[row];
    }
    const float4* src = (const float4*)(emb + (size_t)idx * Dk);
    float4* dst = (float4*)(out + (size_t)row * Dk);
    for (int i = threadIdx.x; i < Dk / 4; i += blockDim.x) dst[i] = src[i];
    if (t < Ll && threadIdx.x == 0) {
        out[(size_t)Bb * Tt * Dk + (size_t)(b * Ll + t)] = (float)idx;
    }
}

extern "C" void kernel_launch(void* const* d_in, const int* in_sizes, int n_in,
                              void* d_out, int out_size, void* d_ws, size_t ws_size,
                              hipStream_t stream) {
    const float* encoder_outs = (const float*)d_in[0];
    const float* embed_weight = (const float*)d_in[1];
    const int* input_ids = (const int*)d_in[2];

    float* out = (float*)d_out;

    float* winv = (float*)d_ws;
    u64* best = (u64*)((char*)d_ws + 131072);
    int* sel = (int*)((char*)d_ws + 147456);
    u64* cand = (u64*)((char*)d_ws + 262144);
    ushort_t* Abf = (ushort_t*)((char*)d_ws + 8454144);
    ushort_t* Wbf = (ushort_t*)((char*)d_ws + 16842752);

    init_best_kernel<<<(Mrows + 255) / 256, 256, 0, stream>>>(best);

    if (ws_size >= WS_NEEDED) {
        convertA_kernel<<<Mrows * Dk / 8 / 256, 256, 0, stream>>>(encoder_outs, Abf);
        convertW_kernel<<<Vv * 64 / 256, 256, 0, stream>>>(embed_weight, Wbf, winv);
        score_topk_kernel<<<NWG, 512, 0, stream>>>(Abf, Wbf, winv, cand);
        topk_kernel<<<Mrows / 4, 256, 0, stream>>>(cand, sel, 2 * NBY);  // 250
    } else {
        wnorm_kernel<<<Vv * 64 / 256, 256, 0, stream>>>(embed_weight, winv);
        dim3 grid(Mrows / FBM, Vv / FBN);
        score_topk_fallback<<<grid, 256, 0, stream>>>(encoder_outs, embed_weight, winv,
                                                      cand);
        topk_kernel<<<Mrows / 4, 256, 0, stream>>>(cand, sel, 2 * FNVB);  // 500
    }
    rescore_kernel<<<Mrows * KCAND / 4, 256, 0, stream>>>(encoder_outs, embed_weight,
                                                          winv, sel, best);
    blend_kernel<<<Bb * Tt, 256, 0, stream>>>(embed_weight, input_ids, best, out);
}